// Round 8
// baseline (609.431 us; speedup 1.0000x reference)
//
#include <hip/hip_runtime.h>
#include <math.h>

#define B_ 2
#define S_ 1024
#define HID 4096
#define NH 32
#define NKV 8
#define HD 128
#define LOG2E 1.44269504088896340736f

typedef short s16x8 __attribute__((ext_vector_type(8)));   // 8 bf16 (4 VGPRs)
typedef float f32x4 __attribute__((ext_vector_type(4)));
typedef unsigned short u16;
typedef u16 u16x4 __attribute__((ext_vector_type(4)));

__device__ __forceinline__ f32x4 mfma16(s16x8 a, s16x8 b, f32x4 c) {
  return __builtin_amdgcn_mfma_f32_16x16x32_bf16(a, b, c, 0, 0, 0);
}
// exact for integer-valued floats |v| <= 127
__device__ __forceinline__ u16 f2bf(float f) {
  union { float f; unsigned u; } v; v.f = f;
  return (u16)(v.u >> 16);
}
__device__ __forceinline__ float get_scale(const unsigned* sc, int slot) {
  return fmaxf(__uint_as_float(sc[slot]) / 127.0f, 1e-8f);
}
__device__ __forceinline__ void gload16(const void* g, void* l) {
  __builtin_amdgcn_global_load_lds(
      (const __attribute__((address_space(1))) unsigned*)g,
      (__attribute__((address_space(3))) unsigned*)l, 16, 0, 0);
}
__device__ __forceinline__ void atomic_absmax(unsigned* out, float m, int lane) {
  #pragma unroll
  for (int o = 32; o >= 1; o >>= 1) m = fmaxf(m, __shfl_xor(m, o));
  if (lane == 0) atomicMax(out, __float_as_uint(m));
}

#define SB_() __builtin_amdgcn_sched_barrier(0)
#define PBAR() do { SB_(); __builtin_amdgcn_s_barrier(); SB_(); } while (0)
#define VM6() do { SB_(); asm volatile("s_waitcnt vmcnt(6)" ::: "memory"); } while (0)
#define VM0() do { SB_(); asm volatile("s_waitcnt vmcnt(0)" ::: "memory"); } while (0)

// ---------------- fused absmax over the 5 input tensors ---------------------
__global__ void absmax5_k(const float4* __restrict__ p0, const float4* __restrict__ p1,
                          const float4* __restrict__ p2, const float4* __restrict__ p3,
                          const float4* __restrict__ p4, unsigned* __restrict__ sc) {
  int r = blockIdx.y;
  const float4* x; int n4;
  if (r == 0)      { x = p0; n4 = B_ * S_ * HID / 4; }
  else if (r == 1) { x = p1; n4 = HID * HID / 4; }
  else if (r == 2) { x = p2; n4 = NKV * HD * HID / 4; }
  else if (r == 3) { x = p3; n4 = NKV * HD * HID / 4; }
  else             { x = p4; n4 = HID * HID / 4; }
  float m = 0.f;
  int stride = gridDim.x * blockDim.x;
  for (int i = blockIdx.x * blockDim.x + threadIdx.x; i < n4; i += stride) {
    float4 v = x[i];
    m = fmaxf(m, fmaxf(fmaxf(fabsf(v.x), fabsf(v.y)), fmaxf(fabsf(v.z), fabsf(v.w))));
  }
  atomic_absmax(sc + r, m, threadIdx.x & 63);
}

// ---------------- fused quantize of the 5 input tensors ---------------------
__global__ void quant5_k(const float4* __restrict__ p0, const float4* __restrict__ p1,
                         const float4* __restrict__ p2, const float4* __restrict__ p3,
                         const float4* __restrict__ p4,
                         u16x4* __restrict__ y0, u16x4* __restrict__ y1,
                         u16x4* __restrict__ y2, u16x4* __restrict__ y3,
                         u16x4* __restrict__ y4, const unsigned* __restrict__ sc) {
  int r = blockIdx.y;
  const float4* x; u16x4* y; int n4;
  if (r == 0)      { x = p0; y = y0; n4 = B_ * S_ * HID / 4; }
  else if (r == 1) { x = p1; y = y1; n4 = HID * HID / 4; }
  else if (r == 2) { x = p2; y = y2; n4 = NKV * HD * HID / 4; }
  else if (r == 3) { x = p3; y = y3; n4 = NKV * HD * HID / 4; }
  else             { x = p4; y = y4; n4 = HID * HID / 4; }
  float s = get_scale(sc, r);
  int stride = gridDim.x * blockDim.x;
  for (int i = blockIdx.x * blockDim.x + threadIdx.x; i < n4; i += stride) {
    float4 v = x[i];
    u16x4 o;
    o[0] = f2bf(fminf(fmaxf(rintf(v.x / s), -127.f), 127.f));
    o[1] = f2bf(fminf(fmaxf(rintf(v.y / s), -127.f), 127.f));
    o[2] = f2bf(fminf(fmaxf(rintf(v.z / s), -127.f), 127.f));
    o[3] = f2bf(fminf(fmaxf(rintf(v.w / s), -127.f), 127.f));
    y[i] = o;
  }
}

// ---------------- generic quantize (attn output) ----------------------------
__global__ void quant_k(const float4* __restrict__ x, u16x4* __restrict__ y, int n4,
                        const unsigned* __restrict__ sc, int slot) {
  float s = get_scale(sc, slot);
  int stride = gridDim.x * blockDim.x;
  for (int i = blockIdx.x * blockDim.x + threadIdx.x; i < n4; i += stride) {
    float4 v = x[i];
    u16x4 o;
    o[0] = f2bf(fminf(fmaxf(rintf(v.x / s), -127.f), 127.f));
    o[1] = f2bf(fminf(fmaxf(rintf(v.y / s), -127.f), 127.f));
    o[2] = f2bf(fminf(fmaxf(rintf(v.z / s), -127.f), 127.f));
    o[3] = f2bf(fminf(fmaxf(rintf(v.w / s), -127.f), 127.f));
    y[i] = o;
  }
}

// ================= 256x256 8-phase GEMM (T2+T3+T4+T5) ========================
// C[M,N] = (A[M,k0:k0+nkt*64] * B^T) * scale.  BK=64, 8 waves (2M x 4N).
// LDS 128KB.  Steady state at ph4's vmcnt(6): 14 outstanding -> retires 8
// oldest = all of buf1 tile t+1.  TAIL (t=nkt-2): ph2-4 stages guarded off ->
// only 8 outstanding, so drain vmcnt(0) to cover tile nkt-1.  nkt even, >=2.
// atomicC: epilogue uses atomicAdd (split-K reduce; 2 contribs/elem, fp add
// of two values is order-independent -> deterministic).
__device__ __forceinline__ void rdA(const u16* slot, int wm, int lr, int lg,
                                    s16x8 af[4][2]) {
  #pragma unroll
  for (int mi = 0; mi < 4; ++mi) {
    int row = wm * 64 + mi * 16 + lr;
    const char* base = (const char*)slot + row * 128;
    int sw = (row & 7) << 4;
    #pragma unroll
    for (int ks = 0; ks < 2; ++ks)
      af[mi][ks] = *(const s16x8*)(base + ((ks * 64 + lg * 16) ^ sw));
  }
}
__device__ __forceinline__ void rdB(const u16* slot, int wn, int lr, int lg,
                                    s16x8 bf[2][2]) {
  #pragma unroll
  for (int ni = 0; ni < 2; ++ni) {
    int row = wn * 32 + ni * 16 + lr;
    const char* base = (const char*)slot + row * 128;
    int sw = (row & 7) << 4;
    #pragma unroll
    for (int ks = 0; ks < 2; ++ks)
      bf[ni][ks] = *(const s16x8*)(base + ((ks * 64 + lg * 16) ^ sw));
  }
}
template <int PM, int PN>
__device__ __forceinline__ void mfma_phase(f32x4 (&acc)[2][2][4][2],
                                           const s16x8 (&af)[4][2],
                                           const s16x8 (&bf)[2][2]) {
  __builtin_amdgcn_s_setprio(1);
  #pragma unroll
  for (int mi = 0; mi < 4; ++mi)
    #pragma unroll
    for (int ni = 0; ni < 2; ++ni)
      #pragma unroll
      for (int ks = 0; ks < 2; ++ks)
        acc[PM][PN][mi][ni] = mfma16(af[mi][ks], bf[ni][ks], acc[PM][PN][mi][ni]);
  __builtin_amdgcn_s_setprio(0);
}

__device__ void gemm256(const u16* __restrict__ A, const u16* __restrict__ Bm,
                        float* __restrict__ C, int Ncols, int m0, int n0,
                        int k0, int nkt, float scale, unsigned* omax,
                        bool atomicC, u16* S) {
  const int tid = threadIdx.x;
  const int wave = tid >> 6, lane = tid & 63;
  const int lr = lane & 15, lg = lane >> 4;
  const int wm = wave >> 2, wn = wave & 3;
  u16* SA00 = S;          u16* SA01 = S + 8192;
  u16* SB00 = S + 16384;  u16* SB01 = S + 24576;
  u16* SA10 = S + 32768;  u16* SA11 = S + 40960;
  u16* SB10 = S + 49152;  u16* SB11 = S + 57344;
  // staging: thread t covers rows r0, r0+64 at pre-swizzled col ce
  const int r0 = tid >> 3;
  const int ce = (((tid & 7) * 16) ^ ((r0 & 7) << 4)) >> 1;
  const u16* pa0 = A + (size_t)(m0 + r0) * HID + k0 + ce;
  const u16* pa1 = pa0 + (size_t)128 * HID;
  const u16* pb0 = Bm + (size_t)(n0 + r0) * HID + k0 + ce;
  const u16* pb1 = pb0 + (size_t)128 * HID;
  const int wdst = wave * 512;
  f32x4 acc[2][2][4][2] = {};
  s16x8 af[4][2], bf[2][2];

  auto STG = [&](const u16* p, u16* slot, int tcol) {
    const u16* g = p + tcol * 64;
    gload16(g, slot + wdst);
    gload16(g + (size_t)64 * HID, slot + 4096 + wdst);
  };

  // prologue: tile0 complete + 3 half-tiles of tile1 in flight
  STG(pa0, SA00, 0); STG(pb0, SB00, 0); STG(pa1, SA01, 0); STG(pb1, SB01, 0);
  STG(pa0, SA10, 1); STG(pb1, SB11, 1); STG(pa1, SA11, 1);
  VM6(); PBAR();

  #pragma unroll 1
  for (int t = 0; t < nkt; t += 2) {
    const bool g2 = t + 2 < nkt, g3 = t + 3 < nkt;
    // ph1 (0,0) on tile t (buf0)
    rdA(SA00, wm, lr, lg, af); rdB(SB00, wn, lr, lg, bf);
    STG(pb0, SB10, t + 1);
    PBAR(); mfma_phase<0, 0>(acc, af, bf); PBAR();
    // ph2 (0,1)
    rdB(SB01, wn, lr, lg, bf);
    if (g2) STG(pa0, SA00, t + 2);
    PBAR(); mfma_phase<0, 1>(acc, af, bf); PBAR();
    // ph3 (1,1)
    rdA(SA01, wm, lr, lg, af);
    if (g2) STG(pb1, SB01, t + 2);
    PBAR(); mfma_phase<1, 1>(acc, af, bf); PBAR();
    // ph4 (1,0)
    rdB(SB00, wn, lr, lg, bf);
    if (g2) STG(pa1, SA01, t + 2);
    PBAR(); mfma_phase<1, 0>(acc, af, bf);
    if (g2) { VM6(); } else { VM0(); }  // tail: drain last-tile stages fully
    PBAR();
    // ph5 (0,0) on tile t+1 (buf1)
    rdA(SA10, wm, lr, lg, af); rdB(SB10, wn, lr, lg, bf);
    if (g2) STG(pb0, SB00, t + 2);
    PBAR(); mfma_phase<0, 0>(acc, af, bf); PBAR();
    // ph6 (0,1)
    rdB(SB11, wn, lr, lg, bf);
    if (g3) STG(pa0, SA10, t + 3);
    PBAR(); mfma_phase<0, 1>(acc, af, bf); PBAR();
    // ph7 (1,1)
    rdA(SA11, wm, lr, lg, af);
    if (g3) STG(pb1, SB11, t + 3);
    PBAR(); mfma_phase<1, 1>(acc, af, bf); PBAR();
    // ph8 (1,0)
    rdB(SB10, wn, lr, lg, bf);
    if (g3) STG(pa1, SA11, t + 3);
    PBAR(); mfma_phase<1, 0>(acc, af, bf); VM6(); PBAR();
  }

  float gm = 0.f;
  #pragma unroll
  for (int mh = 0; mh < 2; ++mh)
    #pragma unroll
    for (int nh = 0; nh < 2; ++nh)
      #pragma unroll
      for (int mi = 0; mi < 4; ++mi)
        #pragma unroll
        for (int ni = 0; ni < 2; ++ni) {
          size_t rbase = (size_t)(m0 + mh * 128 + wm * 64 + mi * 16 + lg * 4);
          int cb = n0 + nh * 128 + wn * 32 + ni * 16 + lr;
          #pragma unroll
          for (int r = 0; r < 4; ++r) {
            float v = acc[mh][nh][mi][ni][r] * scale;
            gm = fmaxf(gm, fabsf(v));
            if (atomicC) atomicAdd(&C[(rbase + r) * (size_t)Ncols + cb], v);
            else C[(rbase + r) * (size_t)Ncols + cb] = v;
          }
        }
  if (omax) atomic_absmax(omax, gm, lane);
}

// fused Q/K/V projection: 192 blocks (8 M-tiles x 24 N-tiles), XCD-swizzled
__global__ __launch_bounds__(512, 1) void gemm_qkv8(
    const u16* __restrict__ Xq, const u16* __restrict__ Wqb,
    const u16* __restrict__ Wkb, const u16* __restrict__ Wvb,
    float* __restrict__ qf, float* __restrict__ kf, float* __restrict__ vf,
    const unsigned* __restrict__ sc, unsigned* __restrict__ vmax) {
  extern __shared__ __align__(16) u16 S[];
  int raw = blockIdx.x;
  int wg = (raw & 7) * 24 + (raw >> 3);
  int bx = wg & 7, by = wg >> 3;
  const u16* Bm; float* C; int Ncols, n0, sslot; unsigned* om = nullptr;
  if (by < 16)      { Bm = Wqb; C = qf; Ncols = HID;      n0 = by * 256;        sslot = 1; }
  else if (by < 20) { Bm = Wkb; C = kf; Ncols = NKV * HD; n0 = (by - 16) * 256; sslot = 2; }
  else              { Bm = Wvb; C = vf; Ncols = NKV * HD; n0 = (by - 20) * 256; sslot = 3; om = vmax; }
  float scale = get_scale(sc, 0) * get_scale(sc, sslot);
  gemm256(Xq, Bm, C, Ncols, bx * 256, n0, 0, 64, scale, om, false, S);
}

// O projection, split-K=2: 256 blocks (128 tiles x 2 K-halves), XCD-swizzled,
// atomicAdd reduce into pre-zeroed out.
__global__ __launch_bounds__(512, 1) void gemm_o8(
    const u16* __restrict__ A, const u16* __restrict__ Bm,
    float* __restrict__ Cout, const unsigned* __restrict__ sc) {
  extern __shared__ __align__(16) u16 S[];
  int raw = blockIdx.x;
  int wg = (raw & 7) * 32 + (raw >> 3);   // 256 = 8 XCD x 32, bijective
  int tile = wg >> 1, half = wg & 1;
  int by = tile & 15, bx = tile >> 4;
  float scale = get_scale(sc, 8) * get_scale(sc, 4);
  gemm256(A, Bm, Cout, HID, bx * 256, by * 256, half * 2048, 32,
          scale, nullptr, true, S);
}

// ---------------- RoPE cos/sin table (pos x 64) -----------------------------
__global__ void rope_tab_k(float2* __restrict__ tab) {
  int i = blockIdx.x * 256 + threadIdx.x;  // 65536
  int pos = i >> 6, d = i & 63;
  float inv = exp2f((float)d * (-13.287712379549449f / 64.0f));
  float ang = (float)pos * inv;
  tab[i] = make_float2(cosf(ang), sinf(ang));
}

// ---------------- RoPE in-place + absmax, q & k fused -----------------------
__global__ void rope2_k(float* __restrict__ qf, float* __restrict__ kf,
                        unsigned* __restrict__ sc, const float2* __restrict__ tab) {
  int reg = blockIdx.y;
  float* q = reg ? kf : qf;
  int nheads = reg ? NKV : NH;
  unsigned* om = sc + (reg ? 6 : 5);
  int total = B_ * S_ * nheads * 64;
  int stride = gridDim.x * blockDim.x;
  float m = 0.f;
  for (int i = blockIdx.x * blockDim.x + threadIdx.x; i < total; i += stride) {
    int d = i & 63;
    int h = (i >> 6) % nheads;
    int bs = i / (64 * nheads);
    int pos = bs & (S_ - 1);
    float2 cs = tab[(pos << 6) + d];
    size_t base = ((size_t)bs * nheads + h) * HD + d;
    float x1 = q[base], x2 = q[base + 64];
    float o1 = x1 * cs.x - x2 * cs.y;
    float o2 = x2 * cs.x + x1 * cs.y;
    q[base] = o1; q[base + 64] = o2;
    m = fmaxf(m, fmaxf(fabsf(o1), fabsf(o2)));
  }
  atomic_absmax(om, m, threadIdx.x & 63);
}

// ---------------- quantize q & k fused --------------------------------------
__global__ void quantqk_k(const float4* __restrict__ qf, const float4* __restrict__ kf,
                          u16x4* __restrict__ qq, u16x4* __restrict__ kq,
                          const unsigned* __restrict__ sc) {
  int reg = blockIdx.y;
  const float4* x = reg ? kf : qf;
  u16x4* y = reg ? kq : qq;
  int n4 = reg ? (B_ * S_ * NKV * HD / 4) : (B_ * S_ * HID / 4);
  float s = get_scale(sc, reg ? 6 : 5);
  int stride = gridDim.x * blockDim.x;
  for (int i = blockIdx.x * blockDim.x + threadIdx.x; i < n4; i += stride) {
    float4 v = x[i];
    u16x4 o;
    o[0] = f2bf(fminf(fmaxf(rintf(v.x / s), -127.f), 127.f));
    o[1] = f2bf(fminf(fmaxf(rintf(v.y / s), -127.f), 127.f));
    o[2] = f2bf(fminf(fmaxf(rintf(v.z / s), -127.f), 127.f));
    o[3] = f2bf(fminf(fmaxf(rintf(v.w / s), -127.f), 127.f));
    y[i] = o;
  }
}

// ---------------- V: quantize + transpose to (B,NKV,HD,S), LDS-tiled --------
__global__ __launch_bounds__(256) void vquant_t_k(const float* __restrict__ vf,
                                                  unsigned* __restrict__ vtw,
                                                  const unsigned* __restrict__ sc) {
  __shared__ u16 Ls[64 * 132];
  float s = get_scale(sc, 7);
  int st = blockIdx.x & 15, kvh = (blockIdx.x >> 4) & 7, b = blockIdx.x >> 7;
  int s0 = st * 64;
  #pragma unroll
  for (int i = 0; i < 8; ++i) {
    int o = i * 256 + threadIdx.x;
    int sr = o >> 5, c4 = o & 31;
    float4 v = *(const float4*)(vf + ((size_t)(b * S_ + s0 + sr)) * (NKV * HD) +
                                kvh * HD + c4 * 4);
    u16x4 w;
    w[0] = f2bf(fminf(fmaxf(rintf(v.x / s), -127.f), 127.f));
    w[1] = f2bf(fminf(fmaxf(rintf(v.y / s), -127.f), 127.f));
    w[2] = f2bf(fminf(fmaxf(rintf(v.z / s), -127.f), 127.f));
    w[3] = f2bf(fminf(fmaxf(rintf(v.w / s), -127.f), 127.f));
    *(u16x4*)(Ls + sr * 132 + c4 * 4) = w;
  }
  __syncthreads();
  #pragma unroll
  for (int i = 0; i < 16; ++i) {
    int o = i * 256 + threadIdx.x;
    int d = o >> 5, sj = o & 31;
    unsigned lo = Ls[(sj * 2) * 132 + d], hi = Ls[(sj * 2 + 1) * 132 + d];
    vtw[(((size_t)(b * NKV + kvh) * HD + d) << 9) + st * 32 + sj] = lo | (hi << 16);
  }
}

// ---------------- two-pass quantized causal GQA attention -------------------
// Depth-1 async staging: double-buffered K/V; tile t+1's gloads issued at the
// TOP of iter t, drained by the end-of-iter __syncthreads (latency hidden
// under QK/softmax/PV).  Ps is wave-private (writer & reader both index
// wave*16+..), so no barrier between P-write and PV (lgkmcnt orders it).
__global__ __launch_bounds__(256) void attn_k(
    const u16* __restrict__ Q, const u16* __restrict__ Kq, const u16* __restrict__ Vt,
    float* __restrict__ O, const unsigned* __restrict__ sc, unsigned* __restrict__ omax) {
  __shared__ __align__(16) u16 Ks[2][64 * 128];
  __shared__ __align__(16) u16 Vs[2][128 * 64];
  __shared__ __align__(16) u16 Ps[64 * 64];
  const int tid = threadIdx.x;
  const int wave = tid >> 6, lane = tid & 63;
  const int lr = lane & 15, lg = lane >> 4;
  const int qp = blockIdx.x & 7;
  const int bh = blockIdx.x >> 3;
  const int h = bh & 31, b = bh >> 5;
  const int kvh = h >> 2;
  const float sq = get_scale(sc, 5), sk = get_scale(sc, 6), sv = get_scale(sc, 7);
  const float c2 = sq * sk * 0.08838834764831845f * LOG2E;
  const int k_rin = lane >> 4;
  const int k_cb0 = (lane & 15) * 16;
  const int v_rin = lane >> 3;
  const int v_cb = ((lane & 7) * 16) ^ ((v_rin & 7) << 4);
  float gmax = 0.f;

  auto stageK = [&](int buf, int kt) {
    #pragma unroll
    for (int i = 0; i < 4; ++i) {
      int ch = wave * 4 + i;
      int row = ch * 4 + k_rin;
      int cb = k_cb0 ^ ((row & 7) << 4);
      gload16(Kq + (size_t)(b * S_ + kt * 64 + row) * (NKV * HD) + kvh * HD + (cb >> 1),
              Ks[buf] + ch * 512);
    }
  };
  auto stageV = [&](int buf, int kt) {
    #pragma unroll
    for (int i = 0; i < 4; ++i) {
      int ch = wave * 4 + i;
      int vrow = ch * 8 + v_rin;
      gload16(Vt + ((size_t)(b * NKV + kvh) * HD + vrow) * S_ + kt * 64 + (v_cb >> 1),
              Vs[buf] + ch * 512);
    }
  };

  for (int pi = 0; pi < 2; ++pi) {
    const int qt = pi ? 15 - qp : qp;
    const int q0 = qt * 64;
    s16x8 aq[4];
    {
      const u16* qp_ = Q + (size_t)(b * S_ + q0 + wave * 16 + lr) * HID + h * HD + lg * 8;
      #pragma unroll
      for (int ks = 0; ks < 4; ++ks) aq[ks] = *(const s16x8*)(qp_ + ks * 32);
    }
    float m2[4], ll[4];
    #pragma unroll
    for (int r = 0; r < 4; ++r) { m2[r] = -1.0e38f; ll[r] = 0.f; }

    // ---- pass 1: per-lane online max/denominator ----
    stageK(0, 0);
    __syncthreads();
    for (int kt = 0; kt <= qt; ++kt) {
      const int p = kt & 1;
      if (kt < qt) stageK(p ^ 1, kt + 1);
      f32x4 sacc[4] = {};
      __builtin_amdgcn_s_setprio(1);
      #pragma unroll
      for (int ks = 0; ks < 4; ++ks)
        #pragma unroll
        for (int n = 0; n < 4; ++n) {
          int row = n * 16 + lr;
          s16x8 bk = *(const s16x8*)((const char*)Ks[p] + row * 256 +
                                     ((ks * 64 + lg * 16) ^ ((row & 7) << 4)));
          sacc[n] = mfma16(aq[ks], bk, sacc[n]);
        }
      __builtin_amdgcn_s_setprio(0);
      #pragma unroll
      for (int r = 0; r < 4; ++r) {
        int qg = q0 + wave * 16 + lg * 4 + r;
        float s0[4];
        #pragma unroll
        for (int n = 0; n < 4; ++n) {
          int kg = kt * 64 + n * 16 + lr;
          s0[n] = (kg <= qg) ? sacc[n][r] * c2 : -INFINITY;
        }
        float tm = fmaxf(fmaxf(s0[0], s0[1]), fmaxf(s0[2], s0[3]));
        if (tm > m2[r]) { ll[r] *= exp2f(m2[r] - tm); m2[r] = tm; }
        ll[r] += exp2f(s0[0] - m2[r]) + exp2f(s0[1] - m2[r]) +
                 exp2f(s0[2] - m2[r]) + exp2f(s0[3] - m2[r]);
      }
      __syncthreads();  // drains this iter's stage loads; guards buffer reuse
    }
    float bias[4];
    #pragma unroll
    for (int r = 0; r < 4; ++r) {
      float m = m2[r], l = ll[r];
      #pragma unroll
      for (int o = 8; o >= 1; o >>= 1) {
        float mo = __shfl_xor(m, o), lo = __shfl_xor(l, o);
        float mn = fmaxf(m, mo);
        l = l * exp2f(m - mn) + lo * exp2f(mo - mn);
        m = mn;
      }
      m2[r] = m;
      bias[r] = __log2f(127.0f / l) - m;
    }

    // ---- pass 2: recompute S, quantize P, PV ----
    f32x4 oacc[8] = {};
    stageK(0, 0); stageV(0, 0);
    __syncthreads();
    for (int kt = 0; kt <= qt; ++kt) {
      const int p = kt & 1;
      if (kt < qt) { stageK(p ^ 1, kt + 1); stageV(p ^ 1, kt + 1); }
      f32x4 sacc[4] = {};
      __builtin_amdgcn_s_setprio(1);
      #pragma unroll
      for (int ks = 0; ks < 4; ++ks)
        #pragma unroll
        for (int n = 0; n < 4; ++n) {
          int row = n * 16 + lr;
          s16x8 bk = *(const s16x8*)((const char*)Ks[p] + row * 256 +
                                     ((ks * 64 + lg * 16) ^ ((row & 7) << 4)));
          sacc[n] = mfma16(aq[ks], bk, sacc[n]);
        }
      __builtin_amdgcn_s_setprio(0);
      #pragma unroll
      for (int r = 0; r < 4; ++r) {
        int qg = q0 + wave * 16 + lg * 4 + r;
        int prow = wave * 16 + lg * 4 + r;
        #pragma unroll
        for (int n = 0; n < 4; ++n) {
          int kg = kt * 64 + n * 16 + lr;
          float a = (kg <= qg) ? fmaf(sacc[n][r], c2, bias[r]) : -INFINITY;
          float p127 = rintf(exp2f(a));
          int col = n * 16 + lr;
          *(u16*)((char*)Ps + prow * 128 + ((col * 2) ^ ((prow & 7) << 4))) = f2bf(p127);
        }
      }
      // Ps is wave-private: lgkmcnt orders ds_write -> ds_read, no barrier.
      __builtin_amdgcn_s_setprio(1);
      #pragma unroll
      for (int ks = 0; ks < 2; ++ks) {
        int prow = wave * 16 + lr;
        s16x8 ap = *(const s16x8*)((const char*)Ps + prow * 128 +
                                   ((ks * 64 + lg * 16) ^ ((prow & 7) << 4)));
        #pragma unroll
        for (int n = 0; n < 8; ++n) {
          int vrow = n * 16 + lr;
          s16x8 bv = *(const s16x8*)((const char*)Vs[p] + vrow * 128 +
                                     ((ks * 64 + lg * 16) ^ ((vrow & 7) << 4)));
          oacc[n] = mfma16(ap, bv, oacc[n]);
        }
      }
      __builtin_amdgcn_s_setprio(0);
      __syncthreads();  // drains this iter's stage loads; guards buffer reuse
    }
    const float pvs = sv * (1.0f / 127.0f);
    #pragma unroll
    for (int n = 0; n < 8; ++n)
      #pragma unroll
      for (int r = 0; r < 4; ++r) {
        float v = oacc[n][r] * pvs;
        gmax = fmaxf(gmax, fabsf(v));
        O[(size_t)(b * S_ + q0 + wave * 16 + lg * 4 + r) * HID + h * HD + n * 16 + lr] = v;
      }
  }
  atomic_absmax(omax, gmax, lane);
}

// ---------------------------------------------------------------------------
extern "C" void kernel_launch(void* const* d_in, const int* in_sizes, int n_in,
                              void* d_out, int out_size, void* d_ws, size_t ws_size,
                              hipStream_t stream) {
  const float* hs = (const float*)d_in[0];
  const float* Wq = (const float*)d_in[3];
  const float* Wk = (const float*)d_in[4];
  const float* Wv = (const float*)d_in[5];
  const float* Wo = (const float*)d_in[6];
  float* out = (float*)d_out;
  char* ws = (char*)d_ws;

  unsigned* sc = (unsigned*)ws;  // 0=x 1=Wq 2=Wk 3=Wv 4=Wo 5=q 6=k 7=v 8=attn_out
  size_t off = 256;
  u16* Xq = (u16*)(ws + off); off += (size_t)B_ * S_ * HID * 2;
  size_t wqb_off = off;
  u16* Wqb = (u16*)(ws + off); off += (size_t)HID * HID * 2;
  u16* Wkb = (u16*)(ws + off); off += (size_t)NKV * HD * HID * 2;
  u16* Wvb = (u16*)(ws + off); off += (size_t)NKV * HD * HID * 2;
  u16* Wob = (u16*)(ws + off); off += (size_t)HID * HID * 2;
  size_t qf_off = off;
  float* qf = (float*)(ws + off); off += (size_t)B_ * S_ * HID * 4;
  float* kf = (float*)(ws + off); off += (size_t)B_ * S_ * NKV * HD * 4;
  float* vf = (float*)(ws + off); off += (size_t)B_ * S_ * NKV * HD * 4;
  u16* qq = (u16*)(ws + off); off += (size_t)B_ * S_ * HID * 2;
  u16* kq = (u16*)(ws + off); off += (size_t)B_ * S_ * NKV * HD * 2;
  u16* vt = (u16*)(ws + off); off += (size_t)B_ * S_ * NKV * HD * 2;
  float2* tab = (float2*)(ws + off); off += (size_t)S_ * 64 * 8;
  float* attnf = (float*)(ws + qf_off);  // alias qf (dead after quantqk)
  u16* attnq = (u16*)(ws + wqb_off);     // alias Wqb (dead after gemm_qkv8)

  hipFuncSetAttribute((const void*)gemm_qkv8,
                      hipFuncAttributeMaxDynamicSharedMemorySize, 131072);
  hipFuncSetAttribute((const void*)gemm_o8,
                      hipFuncAttributeMaxDynamicSharedMemorySize, 131072);

  hipMemsetAsync(sc, 0, 64, stream);
  hipMemsetAsync(out, 0, (size_t)B_ * S_ * HID * 4, stream);  // split-K target

  dim3 blk(256);
  absmax5_k<<<dim3(416, 5), blk, 0, stream>>>(
      (const float4*)hs, (const float4*)Wq, (const float4*)Wk,
      (const float4*)Wv, (const float4*)Wo, sc);
  quant5_k<<<dim3(416, 5), blk, 0, stream>>>(
      (const float4*)hs, (const float4*)Wq, (const float4*)Wk,
      (const float4*)Wv, (const float4*)Wo,
      (u16x4*)Xq, (u16x4*)Wqb, (u16x4*)Wkb, (u16x4*)Wvb, (u16x4*)Wob, sc);
  rope_tab_k<<<256, blk, 0, stream>>>(tab);

  gemm_qkv8<<<192, 512, 131072, stream>>>(Xq, Wqb, Wkb, Wvb, qf, kf, vf, sc, sc + 7);

  rope2_k<<<dim3(512, 2), blk, 0, stream>>>(qf, kf, sc, tab);
  quantqk_k<<<dim3(512, 2), blk, 0, stream>>>((const float4*)qf, (const float4*)kf,
                                              (u16x4*)qq, (u16x4*)kq, sc);
  vquant_t_k<<<256, blk, 0, stream>>>(vf, (unsigned*)vt, sc);

  attn_k<<<512, blk, 0, stream>>>(qq, kq, vt, attnf, sc, sc + 8);

  quant_k<<<2048, blk, 0, stream>>>((const float4*)attnf, (u16x4*)attnq,
                                    B_ * S_ * HID / 4, sc, 8);
  gemm_o8<<<256, 512, 131072, stream>>>(attnq, Wob, out, sc);
}

// Round 9
// 553.502 us; speedup vs baseline: 1.1010x; 1.1010x over previous
//
#include <hip/hip_runtime.h>
#include <math.h>

#define B_ 2
#define S_ 1024
#define HID 4096
#define NH 32
#define NKV 8
#define HD 128
#define LOG2E 1.44269504088896340736f

typedef short s16x8 __attribute__((ext_vector_type(8)));   // 8 bf16 (4 VGPRs)
typedef float f32x4 __attribute__((ext_vector_type(4)));
typedef unsigned short u16;
typedef u16 u16x4 __attribute__((ext_vector_type(4)));

__device__ __forceinline__ f32x4 mfma16(s16x8 a, s16x8 b, f32x4 c) {
  return __builtin_amdgcn_mfma_f32_16x16x32_bf16(a, b, c, 0, 0, 0);
}
// exact for integer-valued floats |v| <= 127
__device__ __forceinline__ u16 f2bf(float f) {
  union { float f; unsigned u; } v; v.f = f;
  return (u16)(v.u >> 16);
}
__device__ __forceinline__ float get_scale(const unsigned* sc, int slot) {
  return fmaxf(__uint_as_float(sc[slot]) / 127.0f, 1e-8f);
}
__device__ __forceinline__ void gload16(const void* g, void* l) {
  __builtin_amdgcn_global_load_lds(
      (const __attribute__((address_space(1))) unsigned*)g,
      (__attribute__((address_space(3))) unsigned*)l, 16, 0, 0);
}
__device__ __forceinline__ void atomic_absmax(unsigned* out, float m, int lane) {
  #pragma unroll
  for (int o = 32; o >= 1; o >>= 1) m = fmaxf(m, __shfl_xor(m, o));
  if (lane == 0) atomicMax(out, __float_as_uint(m));
}

#define SB_() __builtin_amdgcn_sched_barrier(0)
#define PBAR() do { SB_(); __builtin_amdgcn_s_barrier(); SB_(); } while (0)
#define VM6() do { SB_(); asm volatile("s_waitcnt vmcnt(6)" ::: "memory"); } while (0)
#define VM0() do { SB_(); asm volatile("s_waitcnt vmcnt(0)" ::: "memory"); } while (0)

// ---------------- fused absmax over the 5 input tensors ---------------------
__global__ void absmax5_k(const float4* __restrict__ p0, const float4* __restrict__ p1,
                          const float4* __restrict__ p2, const float4* __restrict__ p3,
                          const float4* __restrict__ p4, unsigned* __restrict__ sc) {
  int r = blockIdx.y;
  const float4* x; int n4;
  if (r == 0)      { x = p0; n4 = B_ * S_ * HID / 4; }
  else if (r == 1) { x = p1; n4 = HID * HID / 4; }
  else if (r == 2) { x = p2; n4 = NKV * HD * HID / 4; }
  else if (r == 3) { x = p3; n4 = NKV * HD * HID / 4; }
  else             { x = p4; n4 = HID * HID / 4; }
  float m = 0.f;
  int stride = gridDim.x * blockDim.x;
  for (int i = blockIdx.x * blockDim.x + threadIdx.x; i < n4; i += stride) {
    float4 v = x[i];
    m = fmaxf(m, fmaxf(fmaxf(fabsf(v.x), fabsf(v.y)), fmaxf(fabsf(v.z), fabsf(v.w))));
  }
  atomic_absmax(sc + r, m, threadIdx.x & 63);
}

// ---------------- fused quantize of the 5 input tensors ---------------------
__global__ void quant5_k(const float4* __restrict__ p0, const float4* __restrict__ p1,
                         const float4* __restrict__ p2, const float4* __restrict__ p3,
                         const float4* __restrict__ p4,
                         u16x4* __restrict__ y0, u16x4* __restrict__ y1,
                         u16x4* __restrict__ y2, u16x4* __restrict__ y3,
                         u16x4* __restrict__ y4, const unsigned* __restrict__ sc) {
  int r = blockIdx.y;
  const float4* x; u16x4* y; int n4;
  if (r == 0)      { x = p0; y = y0; n4 = B_ * S_ * HID / 4; }
  else if (r == 1) { x = p1; y = y1; n4 = HID * HID / 4; }
  else if (r == 2) { x = p2; y = y2; n4 = NKV * HD * HID / 4; }
  else if (r == 3) { x = p3; y = y3; n4 = NKV * HD * HID / 4; }
  else             { x = p4; y = y4; n4 = HID * HID / 4; }
  float s = get_scale(sc, r);
  int stride = gridDim.x * blockDim.x;
  for (int i = blockIdx.x * blockDim.x + threadIdx.x; i < n4; i += stride) {
    float4 v = x[i];
    u16x4 o;
    o[0] = f2bf(fminf(fmaxf(rintf(v.x / s), -127.f), 127.f));
    o[1] = f2bf(fminf(fmaxf(rintf(v.y / s), -127.f), 127.f));
    o[2] = f2bf(fminf(fmaxf(rintf(v.z / s), -127.f), 127.f));
    o[3] = f2bf(fminf(fmaxf(rintf(v.w / s), -127.f), 127.f));
    y[i] = o;
  }
}

// ---------------- generic quantize (attn output) ----------------------------
__global__ void quant_k(const float4* __restrict__ x, u16x4* __restrict__ y, int n4,
                        const unsigned* __restrict__ sc, int slot) {
  float s = get_scale(sc, slot);
  int stride = gridDim.x * blockDim.x;
  for (int i = blockIdx.x * blockDim.x + threadIdx.x; i < n4; i += stride) {
    float4 v = x[i];
    u16x4 o;
    o[0] = f2bf(fminf(fmaxf(rintf(v.x / s), -127.f), 127.f));
    o[1] = f2bf(fminf(fmaxf(rintf(v.y / s), -127.f), 127.f));
    o[2] = f2bf(fminf(fmaxf(rintf(v.z / s), -127.f), 127.f));
    o[3] = f2bf(fminf(fmaxf(rintf(v.w / s), -127.f), 127.f));
    y[i] = o;
  }
}

// ---------------- split-K reduce: out = P0 + P1 (scale pre-applied) ---------
__global__ void add_k(const float4* __restrict__ p0, const float4* __restrict__ p1,
                      float4* __restrict__ out, int n4) {
  int stride = gridDim.x * blockDim.x;
  for (int i = blockIdx.x * blockDim.x + threadIdx.x; i < n4; i += stride) {
    float4 a = p0[i], b = p1[i];
    out[i] = make_float4(a.x + b.x, a.y + b.y, a.z + b.z, a.w + b.w);
  }
}

// ================= 256x256 8-phase GEMM (T2+T3+T4+T5) ========================
// C[M,N] = (A[M,k0:k0+nkt*64] * B^T) * scale.  BK=64, 8 waves (2M x 4N).
// LDS 128KB.  Steady state at ph4's vmcnt(6): 14 outstanding -> retires 8
// oldest = all of buf1 tile t+1.  TAIL (t=nkt-2): ph2-4 stages guarded off ->
// only 8 outstanding, so drain vmcnt(0) to cover tile nkt-1.  nkt even, >=2.
__device__ __forceinline__ void rdA(const u16* slot, int wm, int lr, int lg,
                                    s16x8 af[4][2]) {
  #pragma unroll
  for (int mi = 0; mi < 4; ++mi) {
    int row = wm * 64 + mi * 16 + lr;
    const char* base = (const char*)slot + row * 128;
    int sw = (row & 7) << 4;
    #pragma unroll
    for (int ks = 0; ks < 2; ++ks)
      af[mi][ks] = *(const s16x8*)(base + ((ks * 64 + lg * 16) ^ sw));
  }
}
__device__ __forceinline__ void rdB(const u16* slot, int wn, int lr, int lg,
                                    s16x8 bf[2][2]) {
  #pragma unroll
  for (int ni = 0; ni < 2; ++ni) {
    int row = wn * 32 + ni * 16 + lr;
    const char* base = (const char*)slot + row * 128;
    int sw = (row & 7) << 4;
    #pragma unroll
    for (int ks = 0; ks < 2; ++ks)
      bf[ni][ks] = *(const s16x8*)(base + ((ks * 64 + lg * 16) ^ sw));
  }
}
template <int PM, int PN>
__device__ __forceinline__ void mfma_phase(f32x4 (&acc)[2][2][4][2],
                                           const s16x8 (&af)[4][2],
                                           const s16x8 (&bf)[2][2]) {
  __builtin_amdgcn_s_setprio(1);
  #pragma unroll
  for (int mi = 0; mi < 4; ++mi)
    #pragma unroll
    for (int ni = 0; ni < 2; ++ni)
      #pragma unroll
      for (int ks = 0; ks < 2; ++ks)
        acc[PM][PN][mi][ni] = mfma16(af[mi][ks], bf[ni][ks], acc[PM][PN][mi][ni]);
  __builtin_amdgcn_s_setprio(0);
}

__device__ void gemm256(const u16* __restrict__ A, const u16* __restrict__ Bm,
                        float* __restrict__ C, int Ncols, int m0, int n0,
                        int k0, int nkt, float scale, unsigned* omax, u16* S) {
  const int tid = threadIdx.x;
  const int wave = tid >> 6, lane = tid & 63;
  const int lr = lane & 15, lg = lane >> 4;
  const int wm = wave >> 2, wn = wave & 3;
  u16* SA00 = S;          u16* SA01 = S + 8192;
  u16* SB00 = S + 16384;  u16* SB01 = S + 24576;
  u16* SA10 = S + 32768;  u16* SA11 = S + 40960;
  u16* SB10 = S + 49152;  u16* SB11 = S + 57344;
  // staging: thread t covers rows r0, r0+64 at pre-swizzled col ce
  const int r0 = tid >> 3;
  const int ce = (((tid & 7) * 16) ^ ((r0 & 7) << 4)) >> 1;
  const u16* pa0 = A + (size_t)(m0 + r0) * HID + k0 + ce;
  const u16* pa1 = pa0 + (size_t)128 * HID;
  const u16* pb0 = Bm + (size_t)(n0 + r0) * HID + k0 + ce;
  const u16* pb1 = pb0 + (size_t)128 * HID;
  const int wdst = wave * 512;
  f32x4 acc[2][2][4][2] = {};
  s16x8 af[4][2], bf[2][2];

  auto STG = [&](const u16* p, u16* slot, int tcol) {
    const u16* g = p + tcol * 64;
    gload16(g, slot + wdst);
    gload16(g + (size_t)64 * HID, slot + 4096 + wdst);
  };

  // prologue: tile0 complete + 3 half-tiles of tile1 in flight
  STG(pa0, SA00, 0); STG(pb0, SB00, 0); STG(pa1, SA01, 0); STG(pb1, SB01, 0);
  STG(pa0, SA10, 1); STG(pb1, SB11, 1); STG(pa1, SA11, 1);
  VM6(); PBAR();

  #pragma unroll 1
  for (int t = 0; t < nkt; t += 2) {
    const bool g2 = t + 2 < nkt, g3 = t + 3 < nkt;
    // ph1 (0,0) on tile t (buf0)
    rdA(SA00, wm, lr, lg, af); rdB(SB00, wn, lr, lg, bf);
    STG(pb0, SB10, t + 1);
    PBAR(); mfma_phase<0, 0>(acc, af, bf); PBAR();
    // ph2 (0,1)
    rdB(SB01, wn, lr, lg, bf);
    if (g2) STG(pa0, SA00, t + 2);
    PBAR(); mfma_phase<0, 1>(acc, af, bf); PBAR();
    // ph3 (1,1)
    rdA(SA01, wm, lr, lg, af);
    if (g2) STG(pb1, SB01, t + 2);
    PBAR(); mfma_phase<1, 1>(acc, af, bf); PBAR();
    // ph4 (1,0)
    rdB(SB00, wn, lr, lg, bf);
    if (g2) STG(pa1, SA01, t + 2);
    PBAR(); mfma_phase<1, 0>(acc, af, bf);
    if (g2) { VM6(); } else { VM0(); }  // tail: drain last-tile stages fully
    PBAR();
    // ph5 (0,0) on tile t+1 (buf1)
    rdA(SA10, wm, lr, lg, af); rdB(SB10, wn, lr, lg, bf);
    if (g2) STG(pb0, SB00, t + 2);
    PBAR(); mfma_phase<0, 0>(acc, af, bf); PBAR();
    // ph6 (0,1)
    rdB(SB11, wn, lr, lg, bf);
    if (g3) STG(pa0, SA10, t + 3);
    PBAR(); mfma_phase<0, 1>(acc, af, bf); PBAR();
    // ph7 (1,1)
    rdA(SA11, wm, lr, lg, af);
    if (g3) STG(pb1, SB11, t + 3);
    PBAR(); mfma_phase<1, 1>(acc, af, bf); PBAR();
    // ph8 (1,0)
    rdB(SB10, wn, lr, lg, bf);
    if (g3) STG(pa1, SA11, t + 3);
    PBAR(); mfma_phase<1, 0>(acc, af, bf); VM6(); PBAR();
  }

  float gm = 0.f;
  #pragma unroll
  for (int mh = 0; mh < 2; ++mh)
    #pragma unroll
    for (int nh = 0; nh < 2; ++nh)
      #pragma unroll
      for (int mi = 0; mi < 4; ++mi)
        #pragma unroll
        for (int ni = 0; ni < 2; ++ni) {
          size_t rbase = (size_t)(m0 + mh * 128 + wm * 64 + mi * 16 + lg * 4);
          int cb = n0 + nh * 128 + wn * 32 + ni * 16 + lr;
          #pragma unroll
          for (int r = 0; r < 4; ++r) {
            float v = acc[mh][nh][mi][ni][r] * scale;
            gm = fmaxf(gm, fabsf(v));
            C[(rbase + r) * (size_t)Ncols + cb] = v;
          }
        }
  if (omax) atomic_absmax(omax, gm, lane);
}

// fused Q/K/V projection: 192 blocks (8 M-tiles x 24 N-tiles), XCD-swizzled
__global__ __launch_bounds__(512, 1) void gemm_qkv8(
    const u16* __restrict__ Xq, const u16* __restrict__ Wqb,
    const u16* __restrict__ Wkb, const u16* __restrict__ Wvb,
    float* __restrict__ qf, float* __restrict__ kf, float* __restrict__ vf,
    const unsigned* __restrict__ sc, unsigned* __restrict__ vmax) {
  extern __shared__ __align__(16) u16 S[];
  int raw = blockIdx.x;
  int wg = (raw & 7) * 24 + (raw >> 3);
  int bx = wg & 7, by = wg >> 3;
  const u16* Bm; float* C; int Ncols, n0, sslot; unsigned* om = nullptr;
  if (by < 16)      { Bm = Wqb; C = qf; Ncols = HID;      n0 = by * 256;        sslot = 1; }
  else if (by < 20) { Bm = Wkb; C = kf; Ncols = NKV * HD; n0 = (by - 16) * 256; sslot = 2; }
  else              { Bm = Wvb; C = vf; Ncols = NKV * HD; n0 = (by - 20) * 256; sslot = 3; om = vmax; }
  float scale = get_scale(sc, 0) * get_scale(sc, sslot);
  gemm256(Xq, Bm, C, Ncols, bx * 256, n0, 0, 64, scale, om, S);
}

// O projection, split-K=2: 256 blocks (128 tiles x 2 K-halves), XCD-swizzled
__global__ __launch_bounds__(512, 1) void gemm_o8(
    const u16* __restrict__ A, const u16* __restrict__ Bm,
    float* __restrict__ P0, float* __restrict__ P1,
    const unsigned* __restrict__ sc) {
  extern __shared__ __align__(16) u16 S[];
  int raw = blockIdx.x;
  int wg = (raw & 7) * 32 + (raw >> 3);   // 256 = 8 XCD x 32, bijective
  int tile = wg >> 1, half = wg & 1;
  int by = tile & 15, bx = tile >> 4;
  float scale = get_scale(sc, 8) * get_scale(sc, 4);
  gemm256(A, Bm, half ? P1 : P0, HID, bx * 256, by * 256, half * 2048, 32,
          scale, nullptr, S);
}

// ---------------- RoPE cos/sin table (pos x 64) -----------------------------
__global__ void rope_tab_k(float2* __restrict__ tab) {
  int i = blockIdx.x * 256 + threadIdx.x;  // 65536
  int pos = i >> 6, d = i & 63;
  float inv = exp2f((float)d * (-13.287712379549449f / 64.0f));
  float ang = (float)pos * inv;
  tab[i] = make_float2(cosf(ang), sinf(ang));
}

// ---------------- RoPE in-place + absmax, q & k fused -----------------------
__global__ void rope2_k(float* __restrict__ qf, float* __restrict__ kf,
                        unsigned* __restrict__ sc, const float2* __restrict__ tab) {
  int reg = blockIdx.y;
  float* q = reg ? kf : qf;
  int nheads = reg ? NKV : NH;
  unsigned* om = sc + (reg ? 6 : 5);
  int total = B_ * S_ * nheads * 64;
  int stride = gridDim.x * blockDim.x;
  float m = 0.f;
  for (int i = blockIdx.x * blockDim.x + threadIdx.x; i < total; i += stride) {
    int d = i & 63;
    int h = (i >> 6) % nheads;
    int bs = i / (64 * nheads);
    int pos = bs & (S_ - 1);
    float2 cs = tab[(pos << 6) + d];
    size_t base = ((size_t)bs * nheads + h) * HD + d;
    float x1 = q[base], x2 = q[base + 64];
    float o1 = x1 * cs.x - x2 * cs.y;
    float o2 = x2 * cs.x + x1 * cs.y;
    q[base] = o1; q[base + 64] = o2;
    m = fmaxf(m, fmaxf(fabsf(o1), fabsf(o2)));
  }
  atomic_absmax(om, m, threadIdx.x & 63);
}

// ---------------- quantize q & k fused --------------------------------------
__global__ void quantqk_k(const float4* __restrict__ qf, const float4* __restrict__ kf,
                          u16x4* __restrict__ qq, u16x4* __restrict__ kq,
                          const unsigned* __restrict__ sc) {
  int reg = blockIdx.y;
  const float4* x = reg ? kf : qf;
  u16x4* y = reg ? kq : qq;
  int n4 = reg ? (B_ * S_ * NKV * HD / 4) : (B_ * S_ * HID / 4);
  float s = get_scale(sc, reg ? 6 : 5);
  int stride = gridDim.x * blockDim.x;
  for (int i = blockIdx.x * blockDim.x + threadIdx.x; i < n4; i += stride) {
    float4 v = x[i];
    u16x4 o;
    o[0] = f2bf(fminf(fmaxf(rintf(v.x / s), -127.f), 127.f));
    o[1] = f2bf(fminf(fmaxf(rintf(v.y / s), -127.f), 127.f));
    o[2] = f2bf(fminf(fmaxf(rintf(v.z / s), -127.f), 127.f));
    o[3] = f2bf(fminf(fmaxf(rintf(v.w / s), -127.f), 127.f));
    y[i] = o;
  }
}

// ---------------- V: quantize + transpose to (B,NKV,HD,S), LDS-tiled --------
__global__ __launch_bounds__(256) void vquant_t_k(const float* __restrict__ vf,
                                                  unsigned* __restrict__ vtw,
                                                  const unsigned* __restrict__ sc) {
  __shared__ u16 Ls[64 * 132];
  float s = get_scale(sc, 7);
  int st = blockIdx.x & 15, kvh = (blockIdx.x >> 4) & 7, b = blockIdx.x >> 7;
  int s0 = st * 64;
  #pragma unroll
  for (int i = 0; i < 8; ++i) {
    int o = i * 256 + threadIdx.x;
    int sr = o >> 5, c4 = o & 31;
    float4 v = *(const float4*)(vf + ((size_t)(b * S_ + s0 + sr)) * (NKV * HD) +
                                kvh * HD + c4 * 4);
    u16x4 w;
    w[0] = f2bf(fminf(fmaxf(rintf(v.x / s), -127.f), 127.f));
    w[1] = f2bf(fminf(fmaxf(rintf(v.y / s), -127.f), 127.f));
    w[2] = f2bf(fminf(fmaxf(rintf(v.z / s), -127.f), 127.f));
    w[3] = f2bf(fminf(fmaxf(rintf(v.w / s), -127.f), 127.f));
    *(u16x4*)(Ls + sr * 132 + c4 * 4) = w;
  }
  __syncthreads();
  #pragma unroll
  for (int i = 0; i < 16; ++i) {
    int o = i * 256 + threadIdx.x;
    int d = o >> 5, sj = o & 31;
    unsigned lo = Ls[(sj * 2) * 132 + d], hi = Ls[(sj * 2 + 1) * 132 + d];
    vtw[(((size_t)(b * NKV + kvh) * HD + d) << 9) + st * 32 + sj] = lo | (hi << 16);
  }
}

// ---------------- two-pass quantized causal GQA attention -------------------
// Pass 1 uses a FIXED softmax reference point M0 (softmax is invariant to the
// reference; fp32 range easily covers exp2(s*c2 - M0) for int8-quantized
// scores) -> no online-max tracking, no rescale branches.  Causal masking is
// applied only on the diagonal K-tile (interior tiles are fully valid).
// Depth-1 async staging: double-buffered K/V; tile t+1's gloads issued at the
// top of iter t, drained by the end-of-iter __syncthreads.  Ps is
// wave-private (writer & reader both index wave*16+..) -> no mid barrier.
__global__ __launch_bounds__(256) void attn_k(
    const u16* __restrict__ Q, const u16* __restrict__ Kq, const u16* __restrict__ Vt,
    float* __restrict__ O, const unsigned* __restrict__ sc, unsigned* __restrict__ omax) {
  __shared__ __align__(16) u16 Ks[2][64 * 128];
  __shared__ __align__(16) u16 Vs[2][128 * 64];
  __shared__ __align__(16) u16 Ps[64 * 64];
  const int tid = threadIdx.x;
  const int wave = tid >> 6, lane = tid & 63;
  const int lr = lane & 15, lg = lane >> 4;
  const int qp = blockIdx.x & 7;
  const int bh = blockIdx.x >> 3;
  const int h = bh & 31, b = bh >> 5;
  const int kvh = h >> 2;
  const float sq = get_scale(sc, 5), sk = get_scale(sc, 6), sv = get_scale(sc, 7);
  const float c2 = sq * sk * 0.08838834764831845f * LOG2E;
  const float M0 = 32.0f;
  const int k_rin = lane >> 4;
  const int k_cb0 = (lane & 15) * 16;
  const int v_rin = lane >> 3;
  const int v_cb = ((lane & 7) * 16) ^ ((v_rin & 7) << 4);
  float gmax = 0.f;

  auto stageK = [&](int buf, int kt) {
    #pragma unroll
    for (int i = 0; i < 4; ++i) {
      int ch = wave * 4 + i;
      int row = ch * 4 + k_rin;
      int cb = k_cb0 ^ ((row & 7) << 4);
      gload16(Kq + (size_t)(b * S_ + kt * 64 + row) * (NKV * HD) + kvh * HD + (cb >> 1),
              Ks[buf] + ch * 512);
    }
  };
  auto stageV = [&](int buf, int kt) {
    #pragma unroll
    for (int i = 0; i < 4; ++i) {
      int ch = wave * 4 + i;
      int vrow = ch * 8 + v_rin;
      gload16(Vt + ((size_t)(b * NKV + kvh) * HD + vrow) * S_ + kt * 64 + (v_cb >> 1),
              Vs[buf] + ch * 512);
    }
  };

  for (int pi = 0; pi < 2; ++pi) {
    const int qt = pi ? 15 - qp : qp;
    const int q0 = qt * 64;
    s16x8 aq[4];
    {
      const u16* qp_ = Q + (size_t)(b * S_ + q0 + wave * 16 + lr) * HID + h * HD + lg * 8;
      #pragma unroll
      for (int ks = 0; ks < 4; ++ks) aq[ks] = *(const s16x8*)(qp_ + ks * 32);
    }
    float ll[4] = {0.f, 0.f, 0.f, 0.f};

    // ---- pass 1: denominator only, fixed reference M0 ----
    stageK(0, 0);
    __syncthreads();
    for (int kt = 0; kt <= qt; ++kt) {
      const int p = kt & 1;
      if (kt < qt) stageK(p ^ 1, kt + 1);
      f32x4 sacc[4] = {};
      __builtin_amdgcn_s_setprio(1);
      #pragma unroll
      for (int ks = 0; ks < 4; ++ks)
        #pragma unroll
        for (int n = 0; n < 4; ++n) {
          int row = n * 16 + lr;
          s16x8 bk = *(const s16x8*)((const char*)Ks[p] + row * 256 +
                                     ((ks * 64 + lg * 16) ^ ((row & 7) << 4)));
          sacc[n] = mfma16(aq[ks], bk, sacc[n]);
        }
      __builtin_amdgcn_s_setprio(0);
      if (kt < qt) {
        #pragma unroll
        for (int r = 0; r < 4; ++r)
          #pragma unroll
          for (int n = 0; n < 4; ++n)
            ll[r] += exp2f(fmaf(sacc[n][r], c2, -M0));
      } else {
        #pragma unroll
        for (int r = 0; r < 4; ++r) {
          int qg = q0 + wave * 16 + lg * 4 + r;
          #pragma unroll
          for (int n = 0; n < 4; ++n) {
            int kg = kt * 64 + n * 16 + lr;
            float e = exp2f(fmaf(sacc[n][r], c2, -M0));
            ll[r] += (kg <= qg) ? e : 0.f;
          }
        }
      }
      __syncthreads();  // drains this iter's stage loads; guards buffer reuse
    }
    float bias[4];
    #pragma unroll
    for (int r = 0; r < 4; ++r) {
      float l = ll[r];
      #pragma unroll
      for (int o = 8; o >= 1; o >>= 1) l += __shfl_xor(l, o);
      bias[r] = 6.9886846867721655f - __log2f(l) - M0;  // log2(127) - log2(l) - M0
    }

    // ---- pass 2: recompute S, quantize P, PV ----
    f32x4 oacc[8] = {};
    stageK(0, 0); stageV(0, 0);
    __syncthreads();
    for (int kt = 0; kt <= qt; ++kt) {
      const int p = kt & 1;
      if (kt < qt) { stageK(p ^ 1, kt + 1); stageV(p ^ 1, kt + 1); }
      f32x4 sacc[4] = {};
      __builtin_amdgcn_s_setprio(1);
      #pragma unroll
      for (int ks = 0; ks < 4; ++ks)
        #pragma unroll
        for (int n = 0; n < 4; ++n) {
          int row = n * 16 + lr;
          s16x8 bk = *(const s16x8*)((const char*)Ks[p] + row * 256 +
                                     ((ks * 64 + lg * 16) ^ ((row & 7) << 4)));
          sacc[n] = mfma16(aq[ks], bk, sacc[n]);
        }
      __builtin_amdgcn_s_setprio(0);
      if (kt < qt) {
        #pragma unroll
        for (int r = 0; r < 4; ++r) {
          int prow = wave * 16 + lg * 4 + r;
          #pragma unroll
          for (int n = 0; n < 4; ++n) {
            float p127 = rintf(exp2f(fmaf(sacc[n][r], c2, bias[r])));
            int col = n * 16 + lr;
            *(u16*)((char*)Ps + prow * 128 + ((col * 2) ^ ((prow & 7) << 4))) = f2bf(p127);
          }
        }
      } else {
        #pragma unroll
        for (int r = 0; r < 4; ++r) {
          int prow = wave * 16 + lg * 4 + r;
          int qg = q0 + prow;
          #pragma unroll
          for (int n = 0; n < 4; ++n) {
            int kg = kt * 64 + n * 16 + lr;
            float a = fmaf(sacc[n][r], c2, bias[r]);
            float p127 = (kg <= qg) ? rintf(exp2f(a)) : 0.f;
            int col = n * 16 + lr;
            *(u16*)((char*)Ps + prow * 128 + ((col * 2) ^ ((prow & 7) << 4))) = f2bf(p127);
          }
        }
      }
      // Ps is wave-private: lgkmcnt orders ds_write -> ds_read, no barrier.
      __builtin_amdgcn_s_setprio(1);
      #pragma unroll
      for (int ks = 0; ks < 2; ++ks) {
        int prow = wave * 16 + lr;
        s16x8 ap = *(const s16x8*)((const char*)Ps + prow * 128 +
                                   ((ks * 64 + lg * 16) ^ ((prow & 7) << 4)));
        #pragma unroll
        for (int n = 0; n < 8; ++n) {
          int vrow = n * 16 + lr;
          s16x8 bv = *(const s16x8*)((const char*)Vs[p] + vrow * 128 +
                                     ((ks * 64 + lg * 16) ^ ((vrow & 7) << 4)));
          oacc[n] = mfma16(ap, bv, oacc[n]);
        }
      }
      __builtin_amdgcn_s_setprio(0);
      __syncthreads();  // drains this iter's stage loads; guards buffer reuse
    }
    const float pvs = sv * (1.0f / 127.0f);
    #pragma unroll
    for (int n = 0; n < 8; ++n)
      #pragma unroll
      for (int r = 0; r < 4; ++r) {
        float v = oacc[n][r] * pvs;
        gmax = fmaxf(gmax, fabsf(v));
        O[(size_t)(b * S_ + q0 + wave * 16 + lg * 4 + r) * HID + h * HD + n * 16 + lr] = v;
      }
  }
  atomic_absmax(omax, gmax, lane);
}

// ---------------------------------------------------------------------------
extern "C" void kernel_launch(void* const* d_in, const int* in_sizes, int n_in,
                              void* d_out, int out_size, void* d_ws, size_t ws_size,
                              hipStream_t stream) {
  const float* hs = (const float*)d_in[0];
  const float* Wq = (const float*)d_in[3];
  const float* Wk = (const float*)d_in[4];
  const float* Wv = (const float*)d_in[5];
  const float* Wo = (const float*)d_in[6];
  float* out = (float*)d_out;
  char* ws = (char*)d_ws;

  unsigned* sc = (unsigned*)ws;  // 0=x 1=Wq 2=Wk 3=Wv 4=Wo 5=q 6=k 7=v 8=attn_out
  size_t off = 256;
  u16* Xq = (u16*)(ws + off); off += (size_t)B_ * S_ * HID * 2;
  size_t wqb_off = off;
  u16* Wqb = (u16*)(ws + off); off += (size_t)HID * HID * 2;
  u16* Wkb = (u16*)(ws + off); off += (size_t)NKV * HD * HID * 2;
  u16* Wvb = (u16*)(ws + off); off += (size_t)NKV * HD * HID * 2;
  u16* Wob = (u16*)(ws + off); off += (size_t)HID * HID * 2;
  size_t qf_off = off;
  float* qf = (float*)(ws + off); off += (size_t)B_ * S_ * HID * 4;
  size_t kf_off = off;
  float* kf = (float*)(ws + off); off += (size_t)B_ * S_ * NKV * HD * 4;
  float* vf = (float*)(ws + off); off += (size_t)B_ * S_ * NKV * HD * 4;
  u16* qq = (u16*)(ws + off); off += (size_t)B_ * S_ * HID * 2;
  u16* kq = (u16*)(ws + off); off += (size_t)B_ * S_ * NKV * HD * 2;
  u16* vt = (u16*)(ws + off); off += (size_t)B_ * S_ * NKV * HD * 2;
  float2* tab = (float2*)(ws + off); off += (size_t)S_ * 64 * 8;
  float* attnf = (float*)(ws + qf_off);  // alias qf (dead after quantqk)
  u16* attnq = (u16*)(ws + wqb_off);     // alias Wqb (dead after gemm_qkv8)
  // split-K partials for O-proj: both regions dead by the time gemm_o8 runs
  // (attnf consumed by quant_k; kf..vt consumed by attn_k). 32MB each.
  float* P0 = (float*)(ws + qf_off);
  float* P1 = (float*)(ws + kf_off);  // kf+vf+qq+kq+vt span = 40MB >= 32MB

  hipFuncSetAttribute((const void*)gemm_qkv8,
                      hipFuncAttributeMaxDynamicSharedMemorySize, 131072);
  hipFuncSetAttribute((const void*)gemm_o8,
                      hipFuncAttributeMaxDynamicSharedMemorySize, 131072);

  hipMemsetAsync(sc, 0, 64, stream);

  dim3 blk(256);
  absmax5_k<<<dim3(416, 5), blk, 0, stream>>>(
      (const float4*)hs, (const float4*)Wq, (const float4*)Wk,
      (const float4*)Wv, (const float4*)Wo, sc);
  quant5_k<<<dim3(416, 5), blk, 0, stream>>>(
      (const float4*)hs, (const float4*)Wq, (const float4*)Wk,
      (const float4*)Wv, (const float4*)Wo,
      (u16x4*)Xq, (u16x4*)Wqb, (u16x4*)Wkb, (u16x4*)Wvb, (u16x4*)Wob, sc);
  rope_tab_k<<<256, blk, 0, stream>>>(tab);

  gemm_qkv8<<<192, 512, 131072, stream>>>(Xq, Wqb, Wkb, Wvb, qf, kf, vf, sc, sc + 7);

  rope2_k<<<dim3(512, 2), blk, 0, stream>>>(qf, kf, sc, tab);
  quantqk_k<<<dim3(512, 2), blk, 0, stream>>>((const float4*)qf, (const float4*)kf,
                                              (u16x4*)qq, (u16x4*)kq, sc);
  vquant_t_k<<<256, blk, 0, stream>>>(vf, (unsigned*)vt, sc);

  attn_k<<<512, blk, 0, stream>>>(qq, kq, vt, attnf, sc, sc + 8);

  quant_k<<<2048, blk, 0, stream>>>((const float4*)attnf, (u16x4*)attnq,
                                    B_ * S_ * HID / 4, sc, 8);
  gemm_o8<<<256, 512, 131072, stream>>>(attnq, Wob, P0, P1, sc);
  add_k<<<2048, blk, 0, stream>>>((const float4*)P0, (const float4*)P1,
                                  (float4*)out, B_ * S_ * HID / 4);
}